// Round 21
// baseline (362.005 us; speedup 1.0000x reference)
//
#include <hip/hip_runtime.h>

#define CC 64
#define NN 262144            // rows = 8 * 32*32*32
#define NELEM 16777216       // 8*64*32*32*32
#define KK 512
#define ROWS 128             // rows per block
#define NBLK (NN/ROWS)       // 2048
#define TAU 4e-5f
#define CAP 28672

// ws layout (bytes): end = 264256
#define WS_CNT  0
#define WS_PART 64           // 2048 doubles -> 16448
#define WS_B    16448        // 512 floats   -> 18496
#define WS_E1   18496        // 64 KB bf16-hi of -2e, LINEAR layout -> 84032
#define WS_E2   84032        // 64 KB bf16-lo -> 149568
#define WS_LIST 149568       // 28672 uints  -> 264256

typedef short short8 __attribute__((ext_vector_type(8)));
typedef float f32x4 __attribute__((ext_vector_type(4)));

__device__ __forceinline__ unsigned short bf16_rne(float x) {
    unsigned u = __float_as_uint(x);
    unsigned r = u + 0x7FFFu + ((u >> 16) & 1u);
    return (unsigned short)(r >> 16);
}
__device__ __forceinline__ float bf16_back(unsigned short h) {
    return __uint_as_float(((unsigned)h) << 16);
}

// ---------------------------------------------------------------------------
// Prep: exact numpy B_k; bf16 hi/lo of (-2*e) stored LINEAR (B-fragments are
// consumed straight from L2 — no LDS staging, so no swizzle needed).
// ---------------------------------------------------------------------------
__global__ __launch_bounds__(256) void vq_prep(
    const float* __restrict__ cb, unsigned char* __restrict__ ws)
{
#pragma clang fp contract(off)
    const int k = blockIdx.x * 256 + threadIdx.x;
    if (k == 0) *(unsigned*)(ws + WS_CNT) = 0u;

    float e[CC];
    const float4* ep = (const float4*)(cb + k * CC);
    #pragma unroll
    for (int i = 0; i < 16; ++i) {
        float4 v = ep[i];
        e[4*i] = v.x; e[4*i+1] = v.y; e[4*i+2] = v.z; e[4*i+3] = v.w;
    }
    float q[8];
    #pragma unroll
    for (int j = 0; j < 8; ++j) q[j] = e[j] * e[j];
    #pragma unroll
    for (int i = 1; i < 8; ++i) {
        #pragma unroll
        for (int j = 0; j < 8; ++j) { float sq = e[8*i+j] * e[8*i+j]; q[j] = q[j] + sq; }
    }
    ((float*)(ws + WS_B))[k] = ((q[0]+q[1])+(q[2]+q[3]))+((q[4]+q[5])+(q[6]+q[7]));

    char* e1 = (char*)(ws + WS_E1);
    char* e2 = (char*)(ws + WS_E2);
    #pragma unroll
    for (int s = 0; s < 8; ++s) {
        short8 hi, lo;
        #pragma unroll
        for (int j = 0; j < 8; ++j) {
            float v = -2.0f * e[s*8 + j];          // exact (power-of-2 scale)
            unsigned short h = bf16_rne(v);
            hi[j] = (short)h;
            lo[j] = (short)bf16_rne(v - bf16_back(h));
        }
        const int off = k * 128 + s * 16;          // LINEAR
        *(short8*)(e1 + off) = hi;
        *(short8*)(e2 + off) = lo;
    }
}

// ---------------------------------------------------------------------------
// Main: acc = B_k - 2*x.e via seeded MFMA; top-2 (min+med3) with candidate
// index packed in the low 9 mantissa bits. BARRIER-FREE K-loop: B-fragments
// read directly from L2-resident ws (128 KB) with a 2-deep register double
// buffer — deletes all in-loop barriers, global_load_lds, and e-tile ds_reads
// (rounds 14-20: time invariant to occupancy/LDS/CHUNK/ROWS => chained
// LDS-latency + barrier drains were the suspect fixed cost).
// ---------------------------------------------------------------------------
__global__ __launch_bounds__(256, 4) void vq_mfma(
    const float* __restrict__ in, const float* __restrict__ cb,
    unsigned char* __restrict__ ws,
    float* __restrict__ out_q, float* __restrict__ out_idx)
{
#pragma clang fp contract(off)
    __shared__ float  Bl_s[KK];            // 2 KB
    __shared__ float  Al[ROWS];            // 512 B
    __shared__ int    idx_s[ROWS];         // 512 B
    __shared__ double red_s[256];          // 2 KB

    const int tid  = threadIdx.x;
    const int lane = tid & 63;
    const int w    = tid >> 6;
    const int nb   = blockIdx.x * ROWS;
    const int bblk = nb >> 15;                       // 128-row blocks never cross batch
    const float* xbase = in + ((size_t)bblk << 21) + (nb & 32767);

    // exact numpy A_n (pairwise-8) for the loss — one thread per row
    if (tid < ROWS) {
        const float* xa = xbase + tid;
        float r[8];
        #pragma unroll
        for (int j = 0; j < 8; ++j) { float v = xa[(size_t)j << 15]; r[j] = v * v; }
        #pragma unroll
        for (int i = 1; i < 8; ++i) {
            #pragma unroll
            for (int j = 0; j < 8; ++j) {
                float v = xa[(size_t)(8*i + j) << 15];
                float sq = v * v;
                r[j] = r[j] + sq;
            }
        }
        Al[tid] = ((r[0]+r[1])+(r[2]+r[3]))+((r[4]+r[5])+(r[6]+r[7]));
    }
    {
        const float* wsB = (const float*)(ws + WS_B);
        Bl_s[tid] = wsB[tid]; Bl_s[tid + 256] = wsB[tid + 256];
    }

    // A-fragments: rows nb + w*32 + rt*16 + (lane&15), channels (lane>>4)*8+j (+32)
    short8 a1[2][2], a2[2][2];
    {
        const int c0 = (lane >> 4) * 8;
        #pragma unroll
        for (int rt = 0; rt < 2; ++rt) {
            const float* xp = xbase + (w*32 + rt*16 + (lane & 15));
            #pragma unroll
            for (int j = 0; j < 8; ++j) {
                float v0 = xp[(size_t)(c0 + j) << 15];
                float v1 = xp[(size_t)(c0 + j + 32) << 15];
                unsigned short h0 = bf16_rne(v0), h1 = bf16_rne(v1);
                a1[rt][0][j] = (short)h0;
                a1[rt][1][j] = (short)h1;
                a2[rt][0][j] = (short)bf16_rne(v0 - bf16_back(h0));
                a2[rt][1][j] = (short)bf16_rne(v1 - bf16_back(h1));
            }
        }
    }
    __syncthreads();   // Al, Bl_s visible (the ONLY pre-epilogue barrier)

    float s1v[2][4], s2v[2][4];
    #pragma unroll
    for (int rt = 0; rt < 2; ++rt)
        #pragma unroll
        for (int r = 0; r < 4; ++r) { s1v[rt][r] = 3.4e38f; s2v[rt][r] = 3.4e38f; }

    const unsigned lanec = (unsigned)(lane & 15);

    // B-fragment base pointers: code codeL = kt*16 + (lane&15), half h at
    // byte offset codeL*128 + h*64 + (lane>>4)*16  (linear prep layout).
    const char* e1g = (const char*)(ws + WS_E1) + (lane & 15) * 128 + (lane >> 4) * 16;
    const char* e2g = (const char*)(ws + WS_E2) + (lane & 15) * 128 + (lane >> 4) * 16;

    #define LOADB(B1, B2, kt) {                                   \
        const int off_ = (kt) * 2048;                             \
        B1[0] = *(const short8*)(e1g + off_);                     \
        B1[1] = *(const short8*)(e1g + off_ + 64);                \
        B2[0] = *(const short8*)(e2g + off_);                     \
        B2[1] = *(const short8*)(e2g + off_ + 64); }

    auto MFMAT = [&](const short8* B1, const short8* B2, int kt) {
        const float Bs = Bl_s[kt*16 + (lane & 15)];
        const unsigned pc = ((unsigned)kt << 4) | lanec;
        #pragma unroll
        for (int rt = 0; rt < 2; ++rt) {
            f32x4 acc = {Bs, Bs, Bs, Bs};          // seed with ||e||^2
            acc = __builtin_amdgcn_mfma_f32_16x16x32_bf16(a1[rt][0], B1[0], acc, 0, 0, 0);
            acc = __builtin_amdgcn_mfma_f32_16x16x32_bf16(a1[rt][1], B1[1], acc, 0, 0, 0);
            acc = __builtin_amdgcn_mfma_f32_16x16x32_bf16(a2[rt][0], B1[0], acc, 0, 0, 0);
            acc = __builtin_amdgcn_mfma_f32_16x16x32_bf16(a2[rt][1], B1[1], acc, 0, 0, 0);
            acc = __builtin_amdgcn_mfma_f32_16x16x32_bf16(a1[rt][0], B2[0], acc, 0, 0, 0);
            acc = __builtin_amdgcn_mfma_f32_16x16x32_bf16(a1[rt][1], B2[1], acc, 0, 0, 0);
            #pragma unroll
            for (int r = 0; r < 4; ++r) {
                float dp = __uint_as_float((__float_as_uint(acc[r]) & 0xFFFFFE00u) | pc);
                s2v[rt][r] = __builtin_amdgcn_fmed3f(dp, s1v[rt][r], s2v[rt][r]);
                s1v[rt][r] = __builtin_fminf(s1v[rt][r], dp);
            }
        }
    };

    // software-pipelined barrier-free K-loop (2-deep register double buffer,
    // fully unrolled so all buffer indices are static — no scratch)
    {
        short8 pA1[2], pA2[2], pB1[2], pB2[2];
        LOADB(pA1, pA2, 0);
        #pragma unroll
        for (int kt2 = 0; kt2 < 16; ++kt2) {
            const int k0 = 2*kt2;
            LOADB(pB1, pB2, k0 + 1);
            MFMAT(pA1, pA2, k0);
            if (kt2 < 15) LOADB(pA1, pA2, k0 + 2);
            MFMAT(pB1, pB2, k0 + 1);
        }
    }
    #undef LOADB

    // cross-lane top-2 merge (16 codes/group); index rides in the mantissa
    unsigned* cnt  = (unsigned*)(ws + WS_CNT);
    unsigned* list = (unsigned*)(ws + WS_LIST);
    double lsum = 0.0;
    #pragma unroll
    for (int rt = 0; rt < 2; ++rt) {
        #pragma unroll
        for (int r = 0; r < 4; ++r) {
            float s1 = s1v[rt][r], s2 = s2v[rt][r];
            #pragma unroll
            for (int off = 1; off < 16; off <<= 1) {
                float s1o = __shfl_xor(s1, off);
                float s2o = __shfl_xor(s2, off);
                s2 = __builtin_fminf(__builtin_fminf(s2, s2o), __builtin_fmaxf(s1, s1o));
                s1 = __builtin_fminf(s1, s1o);
            }
            if ((lane & 15) == 0) {
                const int rl = w*32 + rt*16 + (lane>>4)*4 + r;
                const int code = (int)(__float_as_uint(s1) & 511u);
                out_idx[nb + rl] = (float)code;
                idx_s[rl] = code;
                if (s2 - s1 < TAU) {
                    unsigned pos = atomicAdd(cnt, 1u);
                    if (pos < CAP) list[pos] = (unsigned)(nb + rl);
                }
                lsum += (double)(Al[rl] + s1);
            }
        }
    }
    red_s[tid] = lsum;
    __syncthreads();   // also publishes idx_s

    // fused quantized write: 2 threads per row (32 channels each), coalesced
    {
        const int row = tid >> 1, c0 = (tid & 1) << 5;
        const int myidx = idx_s[row];
        const float4* cbr = (const float4*)cb + myidx*16 + (c0 >> 2);
        float* qp = out_q + ((size_t)bblk << 21) + (nb & 32767) + row;
        #pragma unroll
        for (int cg = 0; cg < 8; ++cg) {
            float4 ev = cbr[cg];
            qp[(size_t)(c0 + 4*cg + 0) << 15] = ev.x;
            qp[(size_t)(c0 + 4*cg + 1) << 15] = ev.y;
            qp[(size_t)(c0 + 4*cg + 2) << 15] = ev.z;
            qp[(size_t)(c0 + 4*cg + 3) << 15] = ev.w;
        }
    }
    for (int off = 128; off; off >>= 1) {
        if (tid < off) red_s[tid] += red_s[tid + off];
        __syncthreads();
    }
    if (tid == 0) ((double*)(ws + WS_PART))[blockIdx.x] = red_s[0];
}

// ---------------------------------------------------------------------------
// Exact numpy-f32 recheck. One row per wave; x in LDS; one c-sweep with 8
// persistent per-lane code chains (each chain strictly c-sequential = numpy).
// c4 loop unroll(1): 8 ev float4 in flight — round-11's full unroll spilled.
// ---------------------------------------------------------------------------
__global__ __launch_bounds__(256, 2) void vq_recheck(
    const float* __restrict__ in, const float* __restrict__ cb,
    unsigned char* __restrict__ ws,
    float* __restrict__ out_q, float* __restrict__ out_loss,
    float* __restrict__ out_idx)
{
#pragma clang fp contract(off)
    __shared__ float xs[4][CC];
    const int tid  = threadIdx.x;
    const int lane = tid & 63;
    const int w    = tid >> 6;

    if (blockIdx.x == 0 && w == 0) {
        const double* partials = (const double*)(ws + WS_PART);
        double p = 0.0;
        #pragma unroll
        for (int j = 0; j < 32; ++j) p += partials[lane*32 + j];
        #pragma unroll
        for (int off = 1; off < 64; off <<= 1) p += __shfl_xor(p, off);
        if (lane == 0) *out_loss = (float)(1.25 * p / (double)NELEM);
    }

    const unsigned m = *(const unsigned*)(ws + WS_CNT);
    const unsigned* list = (const unsigned*)(ws + WS_LIST);
    const float* Bw = (const float*)(ws + WS_B);
    const unsigned total = (m <= CAP) ? m : NN;    // overflow -> recheck all

    for (unsigned i = blockIdx.x * 4 + w; i < total; i += gridDim.x * 4) {
        const unsigned n = (m <= CAP) ? list[i] : i;
        const int oldidx = (int)out_idx[n];
        const float* xp = in + ((size_t)(n >> 15) << 21) + (n & 32767);

        xs[w][lane] = xp[(size_t)lane << 15];   // lane c holds x[c]; same-wave dep

        // A = numpy pairwise-8 (uniform LDS broadcast reads)
        float r0[8];
        #pragma unroll
        for (int j = 0; j < 8; ++j) { float v = xs[w][j]; r0[j] = v * v; }
        #pragma unroll
        for (int ii = 1; ii < 8; ++ii) {
            #pragma unroll
            for (int j = 0; j < 8; ++j) { float v = xs[w][8*ii + j]; float sq = v * v; r0[j] = r0[j] + sq; }
        }
        const float A = ((r0[0]+r0[1])+(r0[2]+r0[3]))+((r0[4]+r0[5])+(r0[6]+r0[7]));

        // 8 codes per lane (k = jj*64+lane); c-sweep outer, NOT unrolled
        float cacc[8];
        #pragma unroll
        for (int jj = 0; jj < 8; ++jj) cacc[jj] = 0.f;
        const float4* cb4 = (const float4*)cb;
        #pragma unroll 1
        for (int c4 = 0; c4 < 16; ++c4) {
            float4 x4 = *(const float4*)&xs[w][c4 * 4];
            #pragma unroll
            for (int jj = 0; jj < 8; ++jj) {
                float4 ev = cb4[(size_t)(jj*64 + lane) * 16 + c4];
                cacc[jj] = __builtin_fmaf(x4.x, ev.x, cacc[jj]);
                cacc[jj] = __builtin_fmaf(x4.y, ev.y, cacc[jj]);
                cacc[jj] = __builtin_fmaf(x4.z, ev.z, cacc[jj]);
                cacc[jj] = __builtin_fmaf(x4.w, ev.w, cacc[jj]);
            }
        }

        float best = 3.4e38f; int bk = 0;
        #pragma unroll
        for (int jj = 0; jj < 8; ++jj) {
            const int k = jj*64 + lane;
            const float t1 = A + Bw[k];
            const float t2 = 2.0f * cacc[jj];
            const float D = t1 - t2;
            if (D < best) { best = D; bk = k; }   // k increasing per lane -> first-min
        }
        #pragma unroll
        for (int off = 1; off < 64; off <<= 1) {
            float bo = __shfl_xor(best, off);
            int   ko = __shfl_xor(bk, off);
            if (bo < best || (bo == best && ko < bk)) { best = bo; bk = ko; }
        }
        if (bk != oldidx) {
            if (lane == 0) out_idx[n] = (float)bk;
            out_q[((size_t)(n >> 15) << 21) + ((size_t)lane << 15) + (n & 32767)] = cb[bk*CC + lane];
        }
    }
}

extern "C" void kernel_launch(void* const* d_in, const int* in_sizes, int n_in,
                              void* d_out, int out_size, void* d_ws, size_t ws_size,
                              hipStream_t stream) {
    const float* in = (const float*)d_in[0];
    const float* cb = (const float*)d_in[1];
    float* out      = (float*)d_out;
    float* out_q    = out;                    // [8,64,32,32,32]
    float* out_loss = out + NELEM;            // scalar
    float* out_idx  = out + NELEM + 1;        // [262144]
    unsigned char* ws = (unsigned char*)d_ws;

    vq_prep<<<2, 256, 0, stream>>>(cb, ws);
    vq_mfma<<<NBLK, 256, 0, stream>>>(in, cb, ws, out_q, out_idx);
    vq_recheck<<<1024, 256, 0, stream>>>(in, cb, ws, out_q, out_loss, out_idx);
}

// Round 22
// 111.379 us; speedup vs baseline: 3.2502x; 3.2502x over previous
//
#include <hip/hip_runtime.h>

#define CC 64
#define NN 262144            // rows = 8 * 32*32*32
#define NELEM 16777216       // 8*64*32*32*32
#define KK 512
#define CHUNK 128            // codes per LDS chunk
#define NCHUNK 4
#define ROWS 128             // rows per block
#define TAU 4e-5f
#define CAP 28672

// ws layout (bytes): end = 264256
#define WS_CNT  0
#define WS_PART 64           // 2048 doubles -> 16448
#define WS_B    16448        // 512 floats   -> 18496
#define WS_E1   18496        // 64 KB bf16-hi of -2e, pre-swizzled -> 84032
#define WS_E2   84032        // 64 KB bf16-lo -> 149568
#define WS_LIST 149568       // 28672 uints  -> 264256

typedef short short8 __attribute__((ext_vector_type(8)));
typedef float f32x4 __attribute__((ext_vector_type(4)));

__device__ __forceinline__ unsigned short bf16_rne(float x) {
    unsigned u = __float_as_uint(x);
    unsigned r = u + 0x7FFFu + ((u >> 16) & 1u);
    return (unsigned short)(r >> 16);
}
__device__ __forceinline__ float bf16_back(unsigned short h) {
    return __uint_as_float(((unsigned)h) << 16);
}

// ---------------------------------------------------------------------------
// Prep: exact numpy B_k; bf16 hi/lo of (-2*e) stored PRE-SWIZZLED so vq_mfma
// staging is a plain linear copy. Also resets the flag counter.
// ---------------------------------------------------------------------------
__global__ __launch_bounds__(256) void vq_prep(
    const float* __restrict__ cb, unsigned char* __restrict__ ws)
{
#pragma clang fp contract(off)
    const int k = blockIdx.x * 256 + threadIdx.x;
    if (k == 0) *(unsigned*)(ws + WS_CNT) = 0u;

    float e[CC];
    const float4* ep = (const float4*)(cb + k * CC);
    #pragma unroll
    for (int i = 0; i < 16; ++i) {
        float4 v = ep[i];
        e[4*i] = v.x; e[4*i+1] = v.y; e[4*i+2] = v.z; e[4*i+3] = v.w;
    }
    float q[8];
    #pragma unroll
    for (int j = 0; j < 8; ++j) q[j] = e[j] * e[j];
    #pragma unroll
    for (int i = 1; i < 8; ++i) {
        #pragma unroll
        for (int j = 0; j < 8; ++j) { float sq = e[8*i+j] * e[8*i+j]; q[j] = q[j] + sq; }
    }
    ((float*)(ws + WS_B))[k] = ((q[0]+q[1])+(q[2]+q[3]))+((q[4]+q[5])+(q[6]+q[7]));

    char* e1 = (char*)(ws + WS_E1);
    char* e2 = (char*)(ws + WS_E2);
    #pragma unroll
    for (int s = 0; s < 8; ++s) {
        short8 hi, lo;
        #pragma unroll
        for (int j = 0; j < 8; ++j) {
            float v = -2.0f * e[s*8 + j];          // exact (power-of-2 scale)
            unsigned short h = bf16_rne(v);
            hi[j] = (short)h;
            lo[j] = (short)bf16_rne(v - bf16_back(h));
        }
        const int off = k * 128 + ((s * 16) ^ ((k & 7) << 4));
        *(short8*)(e1 + off) = hi;
        *(short8*)(e2 + off) = lo;
    }
}

// ---------------------------------------------------------------------------
// Main: acc = B_k - 2*x.e via seeded MFMA; top-2 (min+med3) with candidate
// index packed in the low 9 mantissa bits. 128 rows/block; global_load_lds
// staging. FINAL known-good config (111.5 us, reproduced twice):
//  - plain builtins only (r13: v_and_or_b32 asm corrupted scores)
//  - separate recheck kernel (r17/18: fusion = +30-120 us stall)
//  - (256,4), CHUNK=128, ROWS=128 — every other point on the occupancy/
//    LDS/CHUNK/ROWS/barrier-free axes measured equal or worse (r14-r21)
// ---------------------------------------------------------------------------
__global__ __launch_bounds__(256, 4) void vq_mfma(
    const float* __restrict__ in, const float* __restrict__ cb,
    unsigned char* __restrict__ ws,
    float* __restrict__ out_q, float* __restrict__ out_idx)
{
#pragma clang fp contract(off)
    __shared__ short  e1s[CHUNK * CC];     // 16 KB
    __shared__ short  e2s[CHUNK * CC];     // 16 KB
    __shared__ float  Bl_s[KK];            // 2 KB
    __shared__ float  Al[ROWS];            // 512 B
    __shared__ int    idx_s[ROWS];         // 512 B
    __shared__ double red_s[256];          // 2 KB

    const int tid  = threadIdx.x;
    const int lane = tid & 63;
    const int w    = tid >> 6;
    const int nb   = blockIdx.x * ROWS;
    const int bblk = nb >> 15;                       // 128-row blocks never cross batch
    const float* xbase = in + ((size_t)bblk << 21) + (nb & 32767);

    // exact numpy A_n (pairwise-8) for the loss — one thread per row
    if (tid < ROWS) {
        const float* xa = xbase + tid;
        float r[8];
        #pragma unroll
        for (int j = 0; j < 8; ++j) { float v = xa[(size_t)j << 15]; r[j] = v * v; }
        #pragma unroll
        for (int i = 1; i < 8; ++i) {
            #pragma unroll
            for (int j = 0; j < 8; ++j) {
                float v = xa[(size_t)(8*i + j) << 15];
                float sq = v * v;
                r[j] = r[j] + sq;
            }
        }
        Al[tid] = ((r[0]+r[1])+(r[2]+r[3]))+((r[4]+r[5])+(r[6]+r[7]));
    }
    {
        const float* wsB = (const float*)(ws + WS_B);
        Bl_s[tid] = wsB[tid]; Bl_s[tid + 256] = wsB[tid + 256];
    }
    __syncthreads();

    // A-fragments: rows nb + w*32 + rt*16 + (lane&15), channels (lane>>4)*8+j (+32)
    short8 a1[2][2], a2[2][2];
    {
        const int c0 = (lane >> 4) * 8;
        #pragma unroll
        for (int rt = 0; rt < 2; ++rt) {
            const float* xp = xbase + (w*32 + rt*16 + (lane & 15));
            #pragma unroll
            for (int j = 0; j < 8; ++j) {
                float v0 = xp[(size_t)(c0 + j) << 15];
                float v1 = xp[(size_t)(c0 + j + 32) << 15];
                unsigned short h0 = bf16_rne(v0), h1 = bf16_rne(v1);
                a1[rt][0][j] = (short)h0;
                a1[rt][1][j] = (short)h1;
                a2[rt][0][j] = (short)bf16_rne(v0 - bf16_back(h0));
                a2[rt][1][j] = (short)bf16_rne(v1 - bf16_back(h1));
            }
        }
    }

    float s1v[2][4], s2v[2][4];
    #pragma unroll
    for (int rt = 0; rt < 2; ++rt)
        #pragma unroll
        for (int r = 0; r < 4; ++r) { s1v[rt][r] = 3.4e38f; s2v[rt][r] = 3.4e38f; }

    const unsigned lanec = (unsigned)(lane & 15);

    for (int ch = 0; ch < NCHUNK; ++ch) {
        __syncthreads();
        // stage pre-swizzled hi/lo chunk via async global->LDS (16B/lane, linear)
        {
            const char* s1p = (const char*)(ws + WS_E1 + ch * 16384) + tid * 16;
            const char* s2p = (const char*)(ws + WS_E2 + ch * 16384) + tid * 16;
            char* d1p = (char*)e1s + tid * 16;
            char* d2p = (char*)e2s + tid * 16;
            #pragma unroll
            for (int i = 0; i < 4; ++i) {
                __builtin_amdgcn_global_load_lds(
                    (const __attribute__((address_space(1))) unsigned int*)(s1p + i*4096),
                    (__attribute__((address_space(3))) unsigned int*)(d1p + i*4096), 16, 0, 0);
                __builtin_amdgcn_global_load_lds(
                    (const __attribute__((address_space(1))) unsigned int*)(s2p + i*4096),
                    (__attribute__((address_space(3))) unsigned int*)(d2p + i*4096), 16, 0, 0);
            }
        }
        __syncthreads();   // compiler drains vmcnt before barrier

        #pragma unroll
        for (int t16 = 0; t16 < 8; ++t16) {
            const int kt = ch*8 + t16;
            const int codeL = t16*16 + (lane & 15);
            const unsigned pc = ((unsigned)kt << 4) | lanec;
            short8 b1[2], b2[2];
            #pragma unroll
            for (int h = 0; h < 2; ++h) {
                const int byteoff = codeL*128 + (((4*h + (lane>>4)) * 16) ^ ((codeL & 7) << 4));
                b1[h] = *(const short8*)((const char*)e1s + byteoff);
                b2[h] = *(const short8*)((const char*)e2s + byteoff);
            }
            const float Bs = Bl_s[ch*CHUNK + codeL];
            #pragma unroll
            for (int rt = 0; rt < 2; ++rt) {
                f32x4 acc = {Bs, Bs, Bs, Bs};          // seed with ||e||^2
                acc = __builtin_amdgcn_mfma_f32_16x16x32_bf16(a1[rt][0], b1[0], acc, 0, 0, 0);
                acc = __builtin_amdgcn_mfma_f32_16x16x32_bf16(a1[rt][1], b1[1], acc, 0, 0, 0);
                acc = __builtin_amdgcn_mfma_f32_16x16x32_bf16(a2[rt][0], b1[0], acc, 0, 0, 0);
                acc = __builtin_amdgcn_mfma_f32_16x16x32_bf16(a2[rt][1], b1[1], acc, 0, 0, 0);
                acc = __builtin_amdgcn_mfma_f32_16x16x32_bf16(a1[rt][0], b2[0], acc, 0, 0, 0);
                acc = __builtin_amdgcn_mfma_f32_16x16x32_bf16(a1[rt][1], b2[1], acc, 0, 0, 0);
                #pragma unroll
                for (int r = 0; r < 4; ++r) {
                    float dp = __uint_as_float((__float_as_uint(acc[r]) & 0xFFFFFE00u) | pc);
                    s2v[rt][r] = __builtin_amdgcn_fmed3f(dp, s1v[rt][r], s2v[rt][r]);
                    s1v[rt][r] = __builtin_fminf(s1v[rt][r], dp);
                }
            }
        }
    }

    // cross-lane top-2 merge (16 codes/group); index rides in the mantissa
    unsigned* cnt  = (unsigned*)(ws + WS_CNT);
    unsigned* list = (unsigned*)(ws + WS_LIST);
    double lsum = 0.0;
    #pragma unroll
    for (int rt = 0; rt < 2; ++rt) {
        #pragma unroll
        for (int r = 0; r < 4; ++r) {
            float s1 = s1v[rt][r], s2 = s2v[rt][r];
            #pragma unroll
            for (int off = 1; off < 16; off <<= 1) {
                float s1o = __shfl_xor(s1, off);
                float s2o = __shfl_xor(s2, off);
                s2 = __builtin_fminf(__builtin_fminf(s2, s2o), __builtin_fmaxf(s1, s1o));
                s1 = __builtin_fminf(s1, s1o);
            }
            if ((lane & 15) == 0) {
                const int rl = w*32 + rt*16 + (lane>>4)*4 + r;
                const int code = (int)(__float_as_uint(s1) & 511u);
                out_idx[nb + rl] = (float)code;
                idx_s[rl] = code;
                if (s2 - s1 < TAU) {
                    unsigned pos = atomicAdd(cnt, 1u);
                    if (pos < CAP) list[pos] = (unsigned)(nb + rl);
                }
                lsum += (double)(Al[rl] + s1);
            }
        }
    }
    red_s[tid] = lsum;
    __syncthreads();   // also publishes idx_s

    // fused quantized write: 2 threads per row (32 channels each), coalesced
    {
        const int row = tid >> 1, c0 = (tid & 1) << 5;
        const int myidx = idx_s[row];
        const float4* cbr = (const float4*)cb + myidx*16 + (c0 >> 2);
        float* qp = out_q + ((size_t)bblk << 21) + (nb & 32767) + row;
        #pragma unroll
        for (int cg = 0; cg < 8; ++cg) {
            float4 ev = cbr[cg];
            qp[(size_t)(c0 + 4*cg + 0) << 15] = ev.x;
            qp[(size_t)(c0 + 4*cg + 1) << 15] = ev.y;
            qp[(size_t)(c0 + 4*cg + 2) << 15] = ev.z;
            qp[(size_t)(c0 + 4*cg + 3) << 15] = ev.w;
        }
    }
    for (int off = 128; off; off >>= 1) {
        if (tid < off) red_s[tid] += red_s[tid + off];
        __syncthreads();
    }
    if (tid == 0) ((double*)(ws + WS_PART))[blockIdx.x] = red_s[0];
}

// ---------------------------------------------------------------------------
// Exact numpy-f32 recheck. One row per wave; x in LDS; one c-sweep with 8
// persistent per-lane code chains (each chain strictly c-sequential = numpy).
// c4 loop unroll(1): 8 ev float4 in flight — round-11's full unroll spilled.
// ---------------------------------------------------------------------------
__global__ __launch_bounds__(256, 2) void vq_recheck(
    const float* __restrict__ in, const float* __restrict__ cb,
    unsigned char* __restrict__ ws,
    float* __restrict__ out_q, float* __restrict__ out_loss,
    float* __restrict__ out_idx)
{
#pragma clang fp contract(off)
    __shared__ float xs[4][CC];
    const int tid  = threadIdx.x;
    const int lane = tid & 63;
    const int w    = tid >> 6;

    if (blockIdx.x == 0 && w == 0) {
        const double* partials = (const double*)(ws + WS_PART);
        double p = 0.0;
        #pragma unroll
        for (int j = 0; j < 32; ++j) p += partials[lane*32 + j];
        #pragma unroll
        for (int off = 1; off < 64; off <<= 1) p += __shfl_xor(p, off);
        if (lane == 0) *out_loss = (float)(1.25 * p / (double)NELEM);
    }

    const unsigned m = *(const unsigned*)(ws + WS_CNT);
    const unsigned* list = (const unsigned*)(ws + WS_LIST);
    const float* Bw = (const float*)(ws + WS_B);
    const unsigned total = (m <= CAP) ? m : NN;    // overflow -> recheck all

    for (unsigned i = blockIdx.x * 4 + w; i < total; i += gridDim.x * 4) {
        const unsigned n = (m <= CAP) ? list[i] : i;
        const int oldidx = (int)out_idx[n];
        const float* xp = in + ((size_t)(n >> 15) << 21) + (n & 32767);

        xs[w][lane] = xp[(size_t)lane << 15];   // lane c holds x[c]; same-wave dep

        // A = numpy pairwise-8 (uniform LDS broadcast reads)
        float r0[8];
        #pragma unroll
        for (int j = 0; j < 8; ++j) { float v = xs[w][j]; r0[j] = v * v; }
        #pragma unroll
        for (int ii = 1; ii < 8; ++ii) {
            #pragma unroll
            for (int j = 0; j < 8; ++j) { float v = xs[w][8*ii + j]; float sq = v * v; r0[j] = r0[j] + sq; }
        }
        const float A = ((r0[0]+r0[1])+(r0[2]+r0[3]))+((r0[4]+r0[5])+(r0[6]+r0[7]));

        // 8 codes per lane (k = jj*64+lane); c-sweep outer, NOT unrolled
        float cacc[8];
        #pragma unroll
        for (int jj = 0; jj < 8; ++jj) cacc[jj] = 0.f;
        const float4* cb4 = (const float4*)cb;
        #pragma unroll 1
        for (int c4 = 0; c4 < 16; ++c4) {
            float4 x4 = *(const float4*)&xs[w][c4 * 4];
            #pragma unroll
            for (int jj = 0; jj < 8; ++jj) {
                float4 ev = cb4[(size_t)(jj*64 + lane) * 16 + c4];
                cacc[jj] = __builtin_fmaf(x4.x, ev.x, cacc[jj]);
                cacc[jj] = __builtin_fmaf(x4.y, ev.y, cacc[jj]);
                cacc[jj] = __builtin_fmaf(x4.z, ev.z, cacc[jj]);
                cacc[jj] = __builtin_fmaf(x4.w, ev.w, cacc[jj]);
            }
        }

        float best = 3.4e38f; int bk = 0;
        #pragma unroll
        for (int jj = 0; jj < 8; ++jj) {
            const int k = jj*64 + lane;
            const float t1 = A + Bw[k];
            const float t2 = 2.0f * cacc[jj];
            const float D = t1 - t2;
            if (D < best) { best = D; bk = k; }   // k increasing per lane -> first-min
        }
        #pragma unroll
        for (int off = 1; off < 64; off <<= 1) {
            float bo = __shfl_xor(best, off);
            int   ko = __shfl_xor(bk, off);
            if (bo < best || (bo == best && ko < bk)) { best = bo; bk = ko; }
        }
        if (bk != oldidx) {
            if (lane == 0) out_idx[n] = (float)bk;
            out_q[((size_t)(n >> 15) << 21) + ((size_t)lane << 15) + (n & 32767)] = cb[bk*CC + lane];
        }
    }
}

extern "C" void kernel_launch(void* const* d_in, const int* in_sizes, int n_in,
                              void* d_out, int out_size, void* d_ws, size_t ws_size,
                              hipStream_t stream) {
    const float* in = (const float*)d_in[0];
    const float* cb = (const float*)d_in[1];
    float* out      = (float*)d_out;
    float* out_q    = out;                    // [8,64,32,32,32]
    float* out_loss = out + NELEM;            // scalar
    float* out_idx  = out + NELEM + 1;        // [262144]
    unsigned char* ws = (unsigned char*)d_ws;

    vq_prep<<<2, 256, 0, stream>>>(cb, ws);
    vq_mfma<<<NN / ROWS, 256, 0, stream>>>(in, cb, ws, out_q, out_idx);
    vq_recheck<<<1024, 256, 0, stream>>>(in, cb, ws, out_q, out_loss, out_idx);
}